// Round 1
// baseline (424.967 us; speedup 1.0000x reference)
//
#include <hip/hip_runtime.h>

#define N_NODES 100000
#define DIM 64
#define N_EDGES 1250000
#define EPS 1e-12f

// One thread per (edge, dim): gather x[src][d], atomic-accumulate into
// sums[dst][d]; lane d==0 also counts the edge.
__global__ void scatter_add_kernel(const float* __restrict__ x,
                                   const int* __restrict__ src,
                                   const int* __restrict__ dst,
                                   float* __restrict__ sums,
                                   float* __restrict__ cnt) {
    long long tid = (long long)blockIdx.x * blockDim.x + threadIdx.x;
    const long long total = (long long)N_EDGES * DIM;
    if (tid >= total) return;
    int e = (int)(tid >> 6);   // edge index
    int d = (int)(tid & 63);   // dim index
    int s = src[e];
    int t = dst[e];
    float v = x[(long long)s * DIM + d];
    atomicAdd(&sums[(long long)t * DIM + d], v);
    if (d == 0) atomicAdd(&cnt[t], 1.0f);
}

// One 64-lane wave per node: agg = sums/max(cnt,1); L2-normalize the row;
// out = relu(2*h).
__global__ void normalize_kernel(const float* __restrict__ sums,
                                 const float* __restrict__ cnt,
                                 float* __restrict__ out) {
    int wave_in_block = threadIdx.x >> 6;
    int node = blockIdx.x * (blockDim.x >> 6) + wave_in_block;
    int d = threadIdx.x & 63;
    if (node >= N_NODES) return;

    float c = cnt[node];
    float agg = sums[(long long)node * DIM + d] / fmaxf(c, 1.0f);

    // butterfly reduce sum of squares across the 64-lane wave
    float sq = agg * agg;
    #pragma unroll
    for (int off = 32; off > 0; off >>= 1) {
        sq += __shfl_xor(sq, off, 64);
    }
    float norm = sqrtf(sq);
    float h = agg / fmaxf(norm, EPS);
    out[(long long)node * DIM + d] = fmaxf(2.0f * h, 0.0f);
}

extern "C" void kernel_launch(void* const* d_in, const int* in_sizes, int n_in,
                              void* d_out, int out_size, void* d_ws, size_t ws_size,
                              hipStream_t stream) {
    const float* x   = (const float*)d_in[0];           // [N_NODES, DIM]
    const int*   ei  = (const int*)d_in[1];             // [2, N_EDGES]
    // d_in[2] = edge_weights — unused by the reference computation.
    float* out = (float*)d_out;

    float* sums = (float*)d_ws;                         // [N_NODES, DIM]
    float* cnt  = sums + (size_t)N_NODES * DIM;         // [N_NODES]

    size_t zero_bytes = ((size_t)N_NODES * DIM + N_NODES) * sizeof(float);
    hipMemsetAsync(d_ws, 0, zero_bytes, stream);

    const int* src = ei;            // edge_index[0]
    const int* dst = ei + N_EDGES;  // edge_index[1]

    const long long total = (long long)N_EDGES * DIM;
    int block = 256;
    long long grid = (total + block - 1) / block;
    scatter_add_kernel<<<(int)grid, block, 0, stream>>>(x, src, dst, sums, cnt);

    int waves_per_block = 256 / 64;
    int nblocks = (N_NODES + waves_per_block - 1) / waves_per_block;
    normalize_kernel<<<nblocks, 256, 0, stream>>>(sums, cnt, out);
}

// Round 2
// 309.102 us; speedup vs baseline: 1.3748x; 1.3748x over previous
//
#include <hip/hip_runtime.h>

#define N_NODES 100000
#define DIM 64
#define N_EDGES 1250000
#define EPS 1e-12f

#define SCAN_CHUNK 1024                       // elements per scan block
#define NB ((N_NODES + SCAN_CHUNK - 1) / SCAN_CHUNK)   // 98 scan blocks

// ---- Pass 1: histogram of destination degrees (int atomics, L2-resident) ----
__global__ void hist_kernel(const int* __restrict__ dst, int* __restrict__ deg) {
    int e = blockIdx.x * blockDim.x + threadIdx.x;
    if (e < N_EDGES) atomicAdd(&deg[dst[e]], 1);
}

// ---- Pass 2a: per-block exclusive scan of deg (1024 elems / 256 threads) ----
__global__ void scan_blocks_kernel(const int* __restrict__ deg,
                                   int* __restrict__ row_start,
                                   int* __restrict__ bsums) {
    __shared__ int lds[256];
    int t = threadIdx.x;
    int base = blockIdx.x * SCAN_CHUNK + t * 4;
    int v[4];
    int sum = 0;
    #pragma unroll
    for (int i = 0; i < 4; ++i) {
        int idx = base + i;
        v[i] = (idx < N_NODES) ? deg[idx] : 0;
        sum += v[i];
    }
    lds[t] = sum;
    __syncthreads();
    // Hillis-Steele inclusive scan over 256 thread-sums
    for (int off = 1; off < 256; off <<= 1) {
        int val = lds[t];
        int add = (t >= off) ? lds[t - off] : 0;
        __syncthreads();
        lds[t] = val + add;
        __syncthreads();
    }
    int excl = (t > 0) ? lds[t - 1] : 0;
    if (t == 255) bsums[blockIdx.x] = lds[255];
    int run = excl;
    #pragma unroll
    for (int i = 0; i < 4; ++i) {
        int idx = base + i;
        if (idx < N_NODES) row_start[idx] = run;
        run += v[i];
    }
}

// ---- Pass 2b: exclusive scan of the 98 block sums (single block) ----
__global__ void scan_bsums_kernel(int* __restrict__ bsums) {
    __shared__ int lds[128];
    int t = threadIdx.x;
    lds[t] = (t < NB) ? bsums[t] : 0;
    __syncthreads();
    for (int off = 1; off < 128; off <<= 1) {
        int val = lds[t];
        int add = (t >= off) ? lds[t - off] : 0;
        __syncthreads();
        lds[t] = val + add;
        __syncthreads();
    }
    int excl = (t > 0) ? lds[t - 1] : 0;
    if (t < NB) bsums[t] = excl;
}

// ---- Pass 2c: add block offsets; init fill cursors ----
__global__ void add_offsets_kernel(int* __restrict__ row_start,
                                   const int* __restrict__ bsums,
                                   int* __restrict__ cursor) {
    int i = blockIdx.x * blockDim.x + threadIdx.x;
    if (i < N_NODES) {
        int rs = row_start[i] + bsums[i / SCAN_CHUNK];
        row_start[i] = rs;
        cursor[i] = rs;
    }
}

// ---- Pass 3: counting-sort fill — adj[] holds src node ids grouped by dst ----
__global__ void fill_adj_kernel(const int* __restrict__ src,
                                const int* __restrict__ dst,
                                int* __restrict__ cursor,
                                int* __restrict__ adj) {
    int e = blockIdx.x * blockDim.x + threadIdx.x;
    if (e < N_EDGES) {
        int t = dst[e];
        int pos = atomicAdd(&cursor[t], 1);
        adj[pos] = src[e];
    }
}

// ---- Pass 4: fused gather-mean + L2-normalize + relu(2h) ----
// One 64-lane wave per node; lane d owns dim d; accumulate in registers.
__global__ void aggregate_kernel(const float* __restrict__ x,
                                 const int* __restrict__ row_start,
                                 const int* __restrict__ deg,
                                 const int* __restrict__ adj,
                                 float* __restrict__ out) {
    int node = blockIdx.x * (blockDim.x >> 6) + (threadIdx.x >> 6);
    int d = threadIdx.x & 63;
    if (node >= N_NODES) return;

    int start = row_start[node];
    int degn  = deg[node];

    float acc = 0.0f;
    for (int base = 0; base < degn; base += 64) {
        int nchunk = min(64, degn - base);
        int sid = 0;
        if (base + d < degn) sid = adj[start + base + d];   // coalesced
        for (int j = 0; j < nchunk; ++j) {
            int s = __shfl(sid, j, 64);                     // broadcast src id
            acc += x[(size_t)s * DIM + d];                  // coalesced 256B row
        }
    }

    float mean = acc / fmaxf((float)degn, 1.0f);

    // wave butterfly reduce of sum of squares
    float sq = mean * mean;
    #pragma unroll
    for (int off = 32; off > 0; off >>= 1) sq += __shfl_xor(sq, off, 64);
    float norm = sqrtf(sq);

    float h = mean / fmaxf(norm, EPS);
    out[(size_t)node * DIM + d] = fmaxf(2.0f * h, 0.0f);
}

extern "C" void kernel_launch(void* const* d_in, const int* in_sizes, int n_in,
                              void* d_out, int out_size, void* d_ws, size_t ws_size,
                              hipStream_t stream) {
    const float* x  = (const float*)d_in[0];    // [N_NODES, DIM]
    const int*   ei = (const int*)d_in[1];      // [2, N_EDGES]
    float* out = (float*)d_out;

    const int* src = ei;
    const int* dst = ei + N_EDGES;

    // workspace layout (ints): deg[N] | row_start[N] | cursor[N] | bsums[128] | adj[E]
    int* deg       = (int*)d_ws;
    int* row_start = deg + N_NODES;
    int* cursor    = row_start + N_NODES;
    int* bsums     = cursor + N_NODES;
    int* adj       = bsums + 128;

    hipMemsetAsync(deg, 0, N_NODES * sizeof(int), stream);

    int eb = (N_EDGES + 255) / 256;
    hist_kernel<<<eb, 256, 0, stream>>>(dst, deg);

    scan_blocks_kernel<<<NB, 256, 0, stream>>>(deg, row_start, bsums);
    scan_bsums_kernel<<<1, 128, 0, stream>>>(bsums);
    int nb2 = (N_NODES + 255) / 256;
    add_offsets_kernel<<<nb2, 256, 0, stream>>>(row_start, bsums, cursor);

    fill_adj_kernel<<<eb, 256, 0, stream>>>(src, dst, cursor, adj);

    int waves_per_block = 256 / 64;
    int agg_blocks = (N_NODES + waves_per_block - 1) / waves_per_block;
    aggregate_kernel<<<agg_blocks, 256, 0, stream>>>(x, row_start, deg, adj, out);
}

// Round 3
// 279.422 us; speedup vs baseline: 1.5209x; 1.1062x over previous
//
#include <hip/hip_runtime.h>

#define N_NODES 100000
#define DIM 64
#define N_EDGES 1250000
#define EPS 1e-12f

#define SCAN_CHUNK 1024
#define NB ((N_NODES + SCAN_CHUNK - 1) / SCAN_CHUNK)   // 98 scan blocks

// ---- Pass 1: histogram of destination degrees (int4-vectorized) ----
__global__ void hist_kernel(const int4* __restrict__ dst4, int* __restrict__ deg) {
    int i = blockIdx.x * blockDim.x + threadIdx.x;
    if (i < N_EDGES / 4) {
        int4 d = dst4[i];
        atomicAdd(&deg[d.x], 1);
        atomicAdd(&deg[d.y], 1);
        atomicAdd(&deg[d.z], 1);
        atomicAdd(&deg[d.w], 1);
    }
}

// ---- Pass 2a: per-block exclusive scan of deg ----
__global__ void scan_blocks_kernel(const int* __restrict__ deg,
                                   int* __restrict__ row_start,
                                   int* __restrict__ bsums) {
    __shared__ int lds[256];
    int t = threadIdx.x;
    int base = blockIdx.x * SCAN_CHUNK + t * 4;
    int v[4];
    int sum = 0;
    #pragma unroll
    for (int i = 0; i < 4; ++i) {
        int idx = base + i;
        v[i] = (idx < N_NODES) ? deg[idx] : 0;
        sum += v[i];
    }
    lds[t] = sum;
    __syncthreads();
    for (int off = 1; off < 256; off <<= 1) {
        int val = lds[t];
        int add = (t >= off) ? lds[t - off] : 0;
        __syncthreads();
        lds[t] = val + add;
        __syncthreads();
    }
    int excl = (t > 0) ? lds[t - 1] : 0;
    if (t == 255) bsums[blockIdx.x] = lds[255];
    int run = excl;
    #pragma unroll
    for (int i = 0; i < 4; ++i) {
        int idx = base + i;
        if (idx < N_NODES) row_start[idx] = run;
        run += v[i];
    }
}

// ---- Pass 2b: exclusive scan of block sums (single block) ----
__global__ void scan_bsums_kernel(int* __restrict__ bsums) {
    __shared__ int lds[128];
    int t = threadIdx.x;
    lds[t] = (t < NB) ? bsums[t] : 0;
    __syncthreads();
    for (int off = 1; off < 128; off <<= 1) {
        int val = lds[t];
        int add = (t >= off) ? lds[t - off] : 0;
        __syncthreads();
        lds[t] = val + add;
        __syncthreads();
    }
    int excl = (t > 0) ? lds[t - 1] : 0;
    if (t < NB) bsums[t] = excl;
}

// ---- Pass 2c: add block offsets; init fill cursors ----
__global__ void add_offsets_kernel(int* __restrict__ row_start,
                                   const int* __restrict__ bsums,
                                   int* __restrict__ cursor) {
    int i = blockIdx.x * blockDim.x + threadIdx.x;
    if (i < N_NODES) {
        int rs = row_start[i] + bsums[i / SCAN_CHUNK];
        row_start[i] = rs;
        cursor[i] = rs;
    }
}

// ---- Pass 3: counting-sort fill (int4-vectorized edge loads) ----
__global__ void fill_adj_kernel(const int4* __restrict__ src4,
                                const int4* __restrict__ dst4,
                                int* __restrict__ cursor,
                                int* __restrict__ adj) {
    int i = blockIdx.x * blockDim.x + threadIdx.x;
    if (i < N_EDGES / 4) {
        int4 s = src4[i];
        int4 d = dst4[i];
        adj[atomicAdd(&cursor[d.x], 1)] = s.x;
        adj[atomicAdd(&cursor[d.y], 1)] = s.y;
        adj[atomicAdd(&cursor[d.z], 1)] = s.z;
        adj[atomicAdd(&cursor[d.w], 1)] = s.w;
    }
}

// ---- Pass 4: fused gather-mean + L2-normalize + relu(2h) ----
// One wave per node. Lane = group g (row slot 0..3) x sub (dim-quad 0..15).
// 4 rows per trip as float4 loads, unrolled x2 -> up to 8 loads in flight.
__global__ void aggregate_kernel(const float* __restrict__ x,
                                 const int* __restrict__ row_start,
                                 const int* __restrict__ deg,
                                 const int* __restrict__ adj,
                                 float* __restrict__ out) {
    int node = blockIdx.x * (blockDim.x >> 6) + (threadIdx.x >> 6);
    if (node >= N_NODES) return;
    int lane = threadIdx.x & 63;
    int g    = lane >> 4;    // which row of the current 4-row strip
    int sub  = lane & 15;    // which float4 of the 64-float row

    int start = row_start[node];
    int degn  = deg[node];

    const float4* __restrict__ x4 = (const float4*)x;   // 16 float4 per row
    float ax = 0.f, ay = 0.f, az = 0.f, aw = 0.f;

    int e = g;
    for (; e + 4 < degn; e += 8) {
        int s0 = adj[start + e];
        int s1 = adj[start + e + 4];
        float4 v0 = x4[(size_t)s0 * 16 + sub];
        float4 v1 = x4[(size_t)s1 * 16 + sub];
        ax += v0.x + v1.x;
        ay += v0.y + v1.y;
        az += v0.z + v1.z;
        aw += v0.w + v1.w;
    }
    if (e < degn) {
        int s0 = adj[start + e];
        float4 v0 = x4[(size_t)s0 * 16 + sub];
        ax += v0.x; ay += v0.y; az += v0.z; aw += v0.w;
    }

    // reduce the 4 row-groups (lanes differing in bits 4,5)
    #pragma unroll
    for (int off = 16; off < 64; off <<= 1) {
        ax += __shfl_xor(ax, off, 64);
        ay += __shfl_xor(ay, off, 64);
        az += __shfl_xor(az, off, 64);
        aw += __shfl_xor(aw, off, 64);
    }

    float inv = 1.0f / fmaxf((float)degn, 1.0f);
    float mx = ax * inv, my = ay * inv, mz = az * inv, mw = aw * inv;

    // sum of squares across the 16 dim-quads (each group holds full row now)
    float ss = mx * mx + my * my + mz * mz + mw * mw;
    #pragma unroll
    for (int off = 1; off < 16; off <<= 1) ss += __shfl_xor(ss, off, 64);

    float scale = 2.0f / fmaxf(sqrtf(ss), EPS);
    if (g == 0) {
        float4 o;
        o.x = fmaxf(mx * scale, 0.0f);
        o.y = fmaxf(my * scale, 0.0f);
        o.z = fmaxf(mz * scale, 0.0f);
        o.w = fmaxf(mw * scale, 0.0f);
        ((float4*)out)[(size_t)node * 16 + sub] = o;
    }
}

extern "C" void kernel_launch(void* const* d_in, const int* in_sizes, int n_in,
                              void* d_out, int out_size, void* d_ws, size_t ws_size,
                              hipStream_t stream) {
    const float* x  = (const float*)d_in[0];
    const int*   ei = (const int*)d_in[1];
    float* out = (float*)d_out;

    const int* src = ei;
    const int* dst = ei + N_EDGES;

    // workspace: deg[N] | row_start[N] | cursor[N] | bsums[128] | adj[E]
    int* deg       = (int*)d_ws;
    int* row_start = deg + N_NODES;
    int* cursor    = row_start + N_NODES;
    int* bsums     = cursor + N_NODES;
    int* adj       = bsums + 128;

    hipMemsetAsync(deg, 0, N_NODES * sizeof(int), stream);

    int eb4 = (N_EDGES / 4 + 255) / 256;
    hist_kernel<<<eb4, 256, 0, stream>>>((const int4*)dst, deg);

    scan_blocks_kernel<<<NB, 256, 0, stream>>>(deg, row_start, bsums);
    scan_bsums_kernel<<<1, 128, 0, stream>>>(bsums);
    int nb2 = (N_NODES + 255) / 256;
    add_offsets_kernel<<<nb2, 256, 0, stream>>>(row_start, bsums, cursor);

    fill_adj_kernel<<<eb4, 256, 0, stream>>>((const int4*)src, (const int4*)dst,
                                             cursor, adj);

    int waves_per_block = 256 / 64;
    int agg_blocks = (N_NODES + waves_per_block - 1) / waves_per_block;
    aggregate_kernel<<<agg_blocks, 256, 0, stream>>>(x, row_start, deg, adj, out);
}

// Round 4
// 206.099 us; speedup vs baseline: 2.0620x; 1.3558x over previous
//
#include <hip/hip_runtime.h>

#define N_NODES 100000
#define DIM 64
#define N_EDGES 1250000
#define EPS 1e-12f

#define SCAN_CHUNK 1024
#define NB ((N_NODES + SCAN_CHUNK - 1) / SCAN_CHUNK)   // 98 scan blocks

// ---- Pass 1: histogram + per-edge rank.
// atomicAdd's return IS this edge's rank among same-dst edges; rank store is
// a coalesced int4 — the atomic's latency is hidden by TLP, and no later
// pass needs atomics.
__global__ void hist_rank_kernel(const int4* __restrict__ dst4,
                                 int* __restrict__ deg,
                                 int4* __restrict__ rank4) {
    int i = blockIdx.x * blockDim.x + threadIdx.x;
    if (i < N_EDGES / 4) {
        int4 d = dst4[i];
        int4 r;
        r.x = atomicAdd(&deg[d.x], 1);
        r.y = atomicAdd(&deg[d.y], 1);
        r.z = atomicAdd(&deg[d.z], 1);
        r.w = atomicAdd(&deg[d.w], 1);
        rank4[i] = r;
    }
}

// ---- Pass 2a: per-block exclusive scan of deg ----
__global__ void scan_blocks_kernel(const int* __restrict__ deg,
                                   int* __restrict__ row_start,
                                   int* __restrict__ bsums) {
    __shared__ int lds[256];
    int t = threadIdx.x;
    int base = blockIdx.x * SCAN_CHUNK + t * 4;
    int v[4];
    int sum = 0;
    #pragma unroll
    for (int i = 0; i < 4; ++i) {
        int idx = base + i;
        v[i] = (idx < N_NODES) ? deg[idx] : 0;
        sum += v[i];
    }
    lds[t] = sum;
    __syncthreads();
    for (int off = 1; off < 256; off <<= 1) {
        int val = lds[t];
        int add = (t >= off) ? lds[t - off] : 0;
        __syncthreads();
        lds[t] = val + add;
        __syncthreads();
    }
    int excl = (t > 0) ? lds[t - 1] : 0;
    if (t == 255) bsums[blockIdx.x] = lds[255];
    int run = excl;
    #pragma unroll
    for (int i = 0; i < 4; ++i) {
        int idx = base + i;
        if (idx < N_NODES) row_start[idx] = run;
        run += v[i];
    }
}

// ---- Pass 2b: exclusive scan of block sums (single block) ----
__global__ void scan_bsums_kernel(int* __restrict__ bsums) {
    __shared__ int lds[128];
    int t = threadIdx.x;
    lds[t] = (t < NB) ? bsums[t] : 0;
    __syncthreads();
    for (int off = 1; off < 128; off <<= 1) {
        int val = lds[t];
        int add = (t >= off) ? lds[t - off] : 0;
        __syncthreads();
        lds[t] = val + add;
        __syncthreads();
    }
    int excl = (t > 0) ? lds[t - 1] : 0;
    if (t < NB) bsums[t] = excl;
}

// ---- Pass 2c: add block offsets to row_start ----
__global__ void add_offsets_kernel(int* __restrict__ row_start,
                                   const int* __restrict__ bsums) {
    int i = blockIdx.x * blockDim.x + threadIdx.x;
    if (i < N_NODES) row_start[i] += bsums[i / SCAN_CHUNK];
}

// ---- Pass 3: scatter fill — NO atomics, no dependency chain.
// pos is fully determined by row_start + precomputed rank; stores are
// fire-and-forget.
__global__ void fill_adj_kernel(const int4* __restrict__ src4,
                                const int4* __restrict__ dst4,
                                const int4* __restrict__ rank4,
                                const int* __restrict__ row_start,
                                int* __restrict__ adj) {
    int i = blockIdx.x * blockDim.x + threadIdx.x;
    if (i < N_EDGES / 4) {
        int4 s = src4[i];
        int4 d = dst4[i];
        int4 r = rank4[i];
        adj[row_start[d.x] + r.x] = s.x;
        adj[row_start[d.y] + r.y] = s.y;
        adj[row_start[d.z] + r.z] = s.z;
        adj[row_start[d.w] + r.w] = s.w;
    }
}

// ---- Pass 4: fused gather-mean + L2-normalize + relu(2h) ----
// One wave per node. Lane = group g (row slot 0..3) x sub (dim-quad 0..15).
// 4 rows per trip as float4 loads, unrolled x2 -> up to 8 loads in flight.
__global__ void aggregate_kernel(const float* __restrict__ x,
                                 const int* __restrict__ row_start,
                                 const int* __restrict__ deg,
                                 const int* __restrict__ adj,
                                 float* __restrict__ out) {
    int node = blockIdx.x * (blockDim.x >> 6) + (threadIdx.x >> 6);
    if (node >= N_NODES) return;
    int lane = threadIdx.x & 63;
    int g    = lane >> 4;
    int sub  = lane & 15;

    int start = row_start[node];
    int degn  = deg[node];

    const float4* __restrict__ x4 = (const float4*)x;
    float ax = 0.f, ay = 0.f, az = 0.f, aw = 0.f;

    int e = g;
    for (; e + 4 < degn; e += 8) {
        int s0 = adj[start + e];
        int s1 = adj[start + e + 4];
        float4 v0 = x4[(size_t)s0 * 16 + sub];
        float4 v1 = x4[(size_t)s1 * 16 + sub];
        ax += v0.x + v1.x;
        ay += v0.y + v1.y;
        az += v0.z + v1.z;
        aw += v0.w + v1.w;
    }
    if (e < degn) {
        int s0 = adj[start + e];
        float4 v0 = x4[(size_t)s0 * 16 + sub];
        ax += v0.x; ay += v0.y; az += v0.z; aw += v0.w;
    }

    #pragma unroll
    for (int off = 16; off < 64; off <<= 1) {
        ax += __shfl_xor(ax, off, 64);
        ay += __shfl_xor(ay, off, 64);
        az += __shfl_xor(az, off, 64);
        aw += __shfl_xor(aw, off, 64);
    }

    float inv = 1.0f / fmaxf((float)degn, 1.0f);
    float mx = ax * inv, my = ay * inv, mz = az * inv, mw = aw * inv;

    float ss = mx * mx + my * my + mz * mz + mw * mw;
    #pragma unroll
    for (int off = 1; off < 16; off <<= 1) ss += __shfl_xor(ss, off, 64);

    float scale = 2.0f / fmaxf(sqrtf(ss), EPS);
    if (g == 0) {
        float4 o;
        o.x = fmaxf(mx * scale, 0.0f);
        o.y = fmaxf(my * scale, 0.0f);
        o.z = fmaxf(mz * scale, 0.0f);
        o.w = fmaxf(mw * scale, 0.0f);
        ((float4*)out)[(size_t)node * 16 + sub] = o;
    }
}

extern "C" void kernel_launch(void* const* d_in, const int* in_sizes, int n_in,
                              void* d_out, int out_size, void* d_ws, size_t ws_size,
                              hipStream_t stream) {
    const float* x  = (const float*)d_in[0];
    const int*   ei = (const int*)d_in[1];
    float* out = (float*)d_out;

    const int* src = ei;
    const int* dst = ei + N_EDGES;

    // workspace: deg[N] | row_start[N] | bsums[128] | rank[E] | adj[E]
    int* deg       = (int*)d_ws;
    int* row_start = deg + N_NODES;
    int* bsums     = row_start + N_NODES;
    int* rank      = bsums + 128;
    int* adj       = rank + N_EDGES;

    hipMemsetAsync(deg, 0, N_NODES * sizeof(int), stream);

    int eb4 = (N_EDGES / 4 + 255) / 256;
    hist_rank_kernel<<<eb4, 256, 0, stream>>>((const int4*)dst, deg, (int4*)rank);

    scan_blocks_kernel<<<NB, 256, 0, stream>>>(deg, row_start, bsums);
    scan_bsums_kernel<<<1, 128, 0, stream>>>(bsums);
    int nb2 = (N_NODES + 255) / 256;
    add_offsets_kernel<<<nb2, 256, 0, stream>>>(row_start, bsums);

    fill_adj_kernel<<<eb4, 256, 0, stream>>>((const int4*)src, (const int4*)dst,
                                             (const int4*)rank, row_start, adj);

    int waves_per_block = 256 / 64;
    int agg_blocks = (N_NODES + waves_per_block - 1) / waves_per_block;
    aggregate_kernel<<<agg_blocks, 256, 0, stream>>>(x, row_start, deg, adj, out);
}

// Round 5
// 201.597 us; speedup vs baseline: 2.1080x; 1.0223x over previous
//
#include <hip/hip_runtime.h>

#define N_NODES 100000
#define DIM 64
#define N_EDGES 1250000
#define EPS 1e-12f

#define SCAN_CHUNK 1024
#define NB ((N_NODES + SCAN_CHUNK - 1) / SCAN_CHUNK)   // 98 scan blocks

// ---- Pass 1: histogram + per-edge rank. ONE edge per thread: 19.5K waves
// hide the atomic round-trip; rank store is coalesced.
__global__ void hist_rank_kernel(const int* __restrict__ dst,
                                 int* __restrict__ deg,
                                 int* __restrict__ rank) {
    int e = blockIdx.x * blockDim.x + threadIdx.x;
    if (e < N_EDGES) rank[e] = atomicAdd(&deg[dst[e]], 1);
}

// ---- Pass 2a: per-block exclusive scan of deg (block-local; bsums fixed later) ----
__global__ void scan_blocks_kernel(const int* __restrict__ deg,
                                   int* __restrict__ row_start,
                                   int* __restrict__ bsums) {
    __shared__ int lds[256];
    int t = threadIdx.x;
    int base = blockIdx.x * SCAN_CHUNK + t * 4;
    int v[4];
    int sum = 0;
    #pragma unroll
    for (int i = 0; i < 4; ++i) {
        int idx = base + i;
        v[i] = (idx < N_NODES) ? deg[idx] : 0;
        sum += v[i];
    }
    lds[t] = sum;
    __syncthreads();
    for (int off = 1; off < 256; off <<= 1) {
        int val = lds[t];
        int add = (t >= off) ? lds[t - off] : 0;
        __syncthreads();
        lds[t] = val + add;
        __syncthreads();
    }
    int excl = (t > 0) ? lds[t - 1] : 0;
    if (t == 255) bsums[blockIdx.x] = lds[255];
    int run = excl;
    #pragma unroll
    for (int i = 0; i < 4; ++i) {
        int idx = base + i;
        if (idx < N_NODES) row_start[idx] = run;
        run += v[i];
    }
}

// ---- Pass 2b: exclusive scan of block sums (single block). Consumers add
// bsums[node>>10] on the fly — no separate add_offsets pass. ----
__global__ void scan_bsums_kernel(int* __restrict__ bsums) {
    __shared__ int lds[128];
    int t = threadIdx.x;
    lds[t] = (t < NB) ? bsums[t] : 0;
    __syncthreads();
    for (int off = 1; off < 128; off <<= 1) {
        int val = lds[t];
        int add = (t >= off) ? lds[t - off] : 0;
        __syncthreads();
        lds[t] = val + add;
        __syncthreads();
    }
    int excl = (t > 0) ? lds[t - 1] : 0;
    if (t < NB) bsums[t] = excl;
}

// ---- Pass 3: scatter fill — no atomics, fire-and-forget stores, 1 edge/thread ----
__global__ void fill_adj_kernel(const int* __restrict__ src,
                                const int* __restrict__ dst,
                                const int* __restrict__ rank,
                                const int* __restrict__ row_start,
                                const int* __restrict__ bsums,
                                int* __restrict__ adj) {
    int e = blockIdx.x * blockDim.x + threadIdx.x;
    if (e < N_EDGES) {
        int d = dst[e];
        int pos = row_start[d] + bsums[d >> 10] + rank[e];
        adj[pos] = src[e];
    }
}

// ---- Pass 4: fused gather-mean + L2-normalize + relu(2h) ----
// One wave per node. 8 row-slots (g=lane>>3); lane covers its row with two
// float4s (cols 4*sub.. and 32+4*sub..). Main loop pairs rows e,e+8 -> 4
// independent 16B loads in flight; typical deg-12 node = 1 main trip.
__global__ void aggregate_kernel(const float* __restrict__ x,
                                 const int* __restrict__ row_start,
                                 const int* __restrict__ bsums,
                                 const int* __restrict__ deg,
                                 const int* __restrict__ adj,
                                 float* __restrict__ out) {
    int node = blockIdx.x * (blockDim.x >> 6) + (threadIdx.x >> 6);
    if (node >= N_NODES) return;
    int lane = threadIdx.x & 63;
    int g    = lane >> 3;   // row slot 0..7
    int sub  = lane & 7;    // float4 index within half-row

    int start = row_start[node] + bsums[node >> 10];
    int degn  = deg[node];

    const float4* __restrict__ x4 = (const float4*)x;   // 16 float4 per row
    float a0x = 0.f, a0y = 0.f, a0z = 0.f, a0w = 0.f;   // cols 4*sub..
    float a1x = 0.f, a1y = 0.f, a1z = 0.f, a1w = 0.f;   // cols 32+4*sub..

    int e = g;
    for (; e + 8 < degn; e += 16) {
        int s0 = adj[start + e];
        int s1 = adj[start + e + 8];
        float4 v0 = x4[(size_t)s0 * 16 + sub];
        float4 v1 = x4[(size_t)s0 * 16 + 8 + sub];
        float4 v2 = x4[(size_t)s1 * 16 + sub];
        float4 v3 = x4[(size_t)s1 * 16 + 8 + sub];
        a0x += v0.x + v2.x; a0y += v0.y + v2.y;
        a0z += v0.z + v2.z; a0w += v0.w + v2.w;
        a1x += v1.x + v3.x; a1y += v1.y + v3.y;
        a1z += v1.z + v3.z; a1w += v1.w + v3.w;
    }
    if (e < degn) {
        int s0 = adj[start + e];
        float4 v0 = x4[(size_t)s0 * 16 + sub];
        float4 v1 = x4[(size_t)s0 * 16 + 8 + sub];
        a0x += v0.x; a0y += v0.y; a0z += v0.z; a0w += v0.w;
        a1x += v1.x; a1y += v1.y; a1z += v1.z; a1w += v1.w;
    }

    // reduce across the 8 row-slots (lane bits 3,4,5)
    #pragma unroll
    for (int off = 8; off < 64; off <<= 1) {
        a0x += __shfl_xor(a0x, off, 64);
        a0y += __shfl_xor(a0y, off, 64);
        a0z += __shfl_xor(a0z, off, 64);
        a0w += __shfl_xor(a0w, off, 64);
        a1x += __shfl_xor(a1x, off, 64);
        a1y += __shfl_xor(a1y, off, 64);
        a1z += __shfl_xor(a1z, off, 64);
        a1w += __shfl_xor(a1w, off, 64);
    }

    float inv = 1.0f / fmaxf((float)degn, 1.0f);
    a0x *= inv; a0y *= inv; a0z *= inv; a0w *= inv;
    a1x *= inv; a1y *= inv; a1z *= inv; a1w *= inv;

    // sum of squares: per-lane partial, then reduce across sub (bits 0,1,2)
    float ss = a0x*a0x + a0y*a0y + a0z*a0z + a0w*a0w
             + a1x*a1x + a1y*a1y + a1z*a1z + a1w*a1w;
    #pragma unroll
    for (int off = 1; off < 8; off <<= 1) ss += __shfl_xor(ss, off, 64);

    float scale = 2.0f / fmaxf(sqrtf(ss), EPS);
    if (g == 0) {
        float4 o0, o1;
        o0.x = fmaxf(a0x * scale, 0.0f); o0.y = fmaxf(a0y * scale, 0.0f);
        o0.z = fmaxf(a0z * scale, 0.0f); o0.w = fmaxf(a0w * scale, 0.0f);
        o1.x = fmaxf(a1x * scale, 0.0f); o1.y = fmaxf(a1y * scale, 0.0f);
        o1.z = fmaxf(a1z * scale, 0.0f); o1.w = fmaxf(a1w * scale, 0.0f);
        ((float4*)out)[(size_t)node * 16 + sub] = o0;
        ((float4*)out)[(size_t)node * 16 + 8 + sub] = o1;
    }
}

extern "C" void kernel_launch(void* const* d_in, const int* in_sizes, int n_in,
                              void* d_out, int out_size, void* d_ws, size_t ws_size,
                              hipStream_t stream) {
    const float* x  = (const float*)d_in[0];
    const int*   ei = (const int*)d_in[1];
    float* out = (float*)d_out;

    const int* src = ei;
    const int* dst = ei + N_EDGES;

    // workspace: deg[N] | row_start[N] | bsums[128] | rank[E] | adj[E]
    int* deg       = (int*)d_ws;
    int* row_start = deg + N_NODES;
    int* bsums     = row_start + N_NODES;
    int* rank      = bsums + 128;
    int* adj       = rank + N_EDGES;

    hipMemsetAsync(deg, 0, N_NODES * sizeof(int), stream);

    int eb = (N_EDGES + 255) / 256;
    hist_rank_kernel<<<eb, 256, 0, stream>>>(dst, deg, rank);

    scan_blocks_kernel<<<NB, 256, 0, stream>>>(deg, row_start, bsums);
    scan_bsums_kernel<<<1, 128, 0, stream>>>(bsums);

    fill_adj_kernel<<<eb, 256, 0, stream>>>(src, dst, rank, row_start, bsums, adj);

    int waves_per_block = 256 / 64;
    int agg_blocks = (N_NODES + waves_per_block - 1) / waves_per_block;
    aggregate_kernel<<<agg_blocks, 256, 0, stream>>>(x, row_start, bsums, deg,
                                                     adj, out);
}